// Round 1
// baseline (1007.143 us; speedup 1.0000x reference)
//
#include <hip/hip_runtime.h>

#define NN 50000
#define NE 800000
#define FDIM 256

// ---------------- CSR build ----------------

__global__ __launch_bounds__(256) void k_hist(const int* __restrict__ dst, int* __restrict__ deg) {
  int e = blockIdx.x * 256 + threadIdx.x;
  if (e < NE) atomicAdd(&deg[dst[e]], 1);
}

__global__ __launch_bounds__(1024) void k_scan(const int* __restrict__ deg, int* __restrict__ offs,
                                               int* __restrict__ fillp) {
  __shared__ int wsum[16];
  __shared__ int s_carry;
  const int tid = threadIdx.x;
  const int lane = tid & 63;
  const int w = tid >> 6;
  if (tid == 0) s_carry = 0;
  __syncthreads();
  for (int base = 0; base < NN; base += 1024) {
    int i = base + tid;
    int v = (i < NN) ? deg[i] : 0;
    int incl = v;
    #pragma unroll
    for (int off = 1; off < 64; off <<= 1) {
      int tmp = __shfl_up(incl, off, 64);
      if (lane >= off) incl += tmp;
    }
    if (lane == 63) wsum[w] = incl;
    __syncthreads();
    if (w == 0 && lane < 16) {
      int s = wsum[lane];
      #pragma unroll
      for (int off = 1; off < 16; off <<= 1) {
        int tmp = __shfl_up(s, off, 64);
        if (lane >= off) s += tmp;
      }
      wsum[lane] = s;  // inclusive scan of wave sums
    }
    __syncthreads();
    int carry = s_carry;
    int woff = (w == 0) ? 0 : wsum[w - 1];
    if (i < NN) {
      int excl = carry + woff + incl - v;
      offs[i] = excl;
      fillp[i] = excl;
    }
    __syncthreads();
    if (tid == 0) s_carry = carry + wsum[15];
    __syncthreads();
  }
  if (threadIdx.x == 0) offs[NN] = s_carry;  // == NE
}

__global__ __launch_bounds__(256) void k_fill(const int* __restrict__ src, const int* __restrict__ dstA,
                                              int* __restrict__ fillp, int2* __restrict__ pairs) {
  int e = blockIdx.x * 256 + threadIdx.x;
  if (e < NE) {
    int d = dstA[e];
    int pos = atomicAdd(&fillp[d], 1);
    pairs[pos] = make_int2(src[e], e);
  }
}

// ---------------- GEMMs ----------------

// P[i][t] = sum_k x[i][k] * W1[c][k][j],  c=t>>6, j=t&63  (K=256, concat over 4 communities)
__global__ __launch_bounds__(256) void k_proj1(const float* __restrict__ x, const float* __restrict__ W1,
                                               float* __restrict__ P) {
  __shared__ __align__(16) float xs[8][256];
  const int t = threadIdx.x;
  const int row0 = blockIdx.x * 8;
  #pragma unroll
  for (int r = 0; r < 8; r++) xs[r][t] = x[(size_t)(row0 + r) * 256 + t];
  __syncthreads();
  const int c = t >> 6, j = t & 63;
  const float* Wp = W1 + c * 16384 + j;
  float acc[8];
  #pragma unroll
  for (int r = 0; r < 8; r++) acc[r] = 0.f;
  for (int k4 = 0; k4 < 64; k4++) {
    float4 xv[8];
    #pragma unroll
    for (int r = 0; r < 8; r++) xv[r] = *reinterpret_cast<const float4*>(&xs[r][k4 * 4]);
    #pragma unroll
    for (int q = 0; q < 4; q++) {
      float wp = Wp[(size_t)(k4 * 4 + q) * 64];
      #pragma unroll
      for (int r = 0; r < 8; r++) {
        float xvq = q == 0 ? xv[r].x : (q == 1 ? xv[r].y : (q == 2 ? xv[r].z : xv[r].w));
        acc[r] = fmaf(xvq, wp, acc[r]);
      }
    }
  }
  #pragma unroll
  for (int r = 0; r < 8; r++) P[(size_t)(row0 + r) * 256 + t] = acc[r];
}

// enc[i][t] = sum_k x[i][k] * encW[k][t] + encb[t]
__global__ __launch_bounds__(256) void k_enc(const float* __restrict__ x, const float* __restrict__ encW,
                                             const float* __restrict__ encb, float* __restrict__ out) {
  __shared__ __align__(16) float xs[8][256];
  const int t = threadIdx.x;
  const int row0 = blockIdx.x * 8;
  #pragma unroll
  for (int r = 0; r < 8; r++) xs[r][t] = x[(size_t)(row0 + r) * 256 + t];
  __syncthreads();
  const float* We = encW + t;
  float acc[8];
  #pragma unroll
  for (int r = 0; r < 8; r++) acc[r] = 0.f;
  for (int k4 = 0; k4 < 64; k4++) {
    float4 xv[8];
    #pragma unroll
    for (int r = 0; r < 8; r++) xv[r] = *reinterpret_cast<const float4*>(&xs[r][k4 * 4]);
    #pragma unroll
    for (int q = 0; q < 4; q++) {
      float we = We[(size_t)(k4 * 4 + q) * 256];
      #pragma unroll
      for (int r = 0; r < 8; r++) {
        float xvq = q == 0 ? xv[r].x : (q == 1 ? xv[r].y : (q == 2 ? xv[r].z : xv[r].w));
        acc[r] = fmaf(xvq, we, acc[r]);
      }
    }
  }
  float be = encb[t];
  #pragma unroll
  for (int r = 0; r < 8; r++) out[(size_t)(row0 + r) * 256 + t] = acc[r] + be;
}

// Block-diagonal projection (layer 2): P[i][t] = sum_m H[i][64c+m] * W1[c][m][j]
__global__ __launch_bounds__(256) void k_proj_bd(const float* __restrict__ H, const float* __restrict__ W1,
                                                 float* __restrict__ P) {
  __shared__ __align__(16) float hs[16][256];
  const int t = threadIdx.x;
  const int c = t >> 6, j = t & 63;
  const int row0 = blockIdx.x * 16;
  float wcol[64];
  #pragma unroll
  for (int m = 0; m < 64; m++) wcol[m] = W1[c * 4096 + m * 64 + j];
  #pragma unroll
  for (int r = 0; r < 16; r++) hs[r][t] = H[(size_t)(row0 + r) * 256 + t];
  __syncthreads();
  #pragma unroll
  for (int r = 0; r < 16; r++) {
    float acc = 0.f;
    #pragma unroll
    for (int m4 = 0; m4 < 16; m4++) {
      float4 hv = *reinterpret_cast<const float4*>(&hs[r][c * 64 + m4 * 4]);
      acc = fmaf(hv.x, wcol[m4 * 4 + 0], acc);
      acc = fmaf(hv.y, wcol[m4 * 4 + 1], acc);
      acc = fmaf(hv.z, wcol[m4 * 4 + 2], acc);
      acc = fmaf(hv.w, wcol[m4 * 4 + 3], acc);
    }
    P[(size_t)(row0 + r) * 256 + t] = acc;
  }
}

// ---------------- fused aggregation + MLP(K=64) + BN stats ----------------
// For each node i: acc[t] = sum_{e in in(i)} ew[c][eid] * P[src][t]
//                  r[t]   = relu(P[i][t] + acc[t] + b1[t])
//                  z[t]   = b2[t] + sum_m r[64c+m] * W2[c][m][j]   -> Z, bn partial sums
#define NPB 32
__global__ __launch_bounds__(256) void k_agg_mlp(const float* __restrict__ P, const int* __restrict__ offs,
                                                 const int2* __restrict__ pairs, const float* __restrict__ ew,
                                                 const float* __restrict__ b1, const float* __restrict__ W2,
                                                 const float* __restrict__ b2, float* __restrict__ Z,
                                                 float* __restrict__ bnsum, float* __restrict__ bnsq) {
  __shared__ __align__(16) float r_lds[256];
  const int t = threadIdx.x;
  const int c = t >> 6, j = t & 63;
  const float* ewc = ew + (size_t)c * NE;
  float w2col[64];
  #pragma unroll
  for (int m = 0; m < 64; m++) w2col[m] = W2[c * 4096 + m * 64 + j];
  const float b1t = b1[t], b2t = b2[t];
  float lsum = 0.f, lsq = 0.f;
  const int i0 = blockIdx.x * NPB;
  for (int ii = 0; ii < NPB; ii++) {
    int i = i0 + ii;
    if (i >= NN) break;  // uniform across block
    const int es = offs[i], ee = offs[i + 1];
    float acc = 0.f;
    for (int e = es; e < ee; e += 4) {
      float pv[4], wv[4];
      #pragma unroll
      for (int q = 0; q < 4; q++) {
        if (e + q < ee) {
          int2 pr = pairs[e + q];
          pv[q] = P[(size_t)pr.x * 256 + t];
          wv[q] = ewc[pr.y];
        } else {
          pv[q] = 0.f;
          wv[q] = 0.f;
        }
      }
      #pragma unroll
      for (int q = 0; q < 4; q++) acc = fmaf(wv[q], pv[q], acc);
    }
    float r = P[(size_t)i * 256 + t] + acc + b1t;
    r = r > 0.f ? r : 0.f;
    __syncthreads();  // previous node's r_lds reads complete
    r_lds[t] = r;
    __syncthreads();
    float z = b2t;
    #pragma unroll
    for (int m4 = 0; m4 < 16; m4++) {
      float4 rv = *reinterpret_cast<const float4*>(&r_lds[c * 64 + m4 * 4]);
      z = fmaf(rv.x, w2col[m4 * 4 + 0], z);
      z = fmaf(rv.y, w2col[m4 * 4 + 1], z);
      z = fmaf(rv.z, w2col[m4 * 4 + 2], z);
      z = fmaf(rv.w, w2col[m4 * 4 + 3], z);
    }
    Z[(size_t)i * 256 + t] = z;
    lsum += z;
    lsq += z * z;
  }
  atomicAdd(&bnsum[t], lsum);
  atomicAdd(&bnsq[t], lsq);
}

// ---------------- BN affine + relu, in place ----------------
__global__ __launch_bounds__(256) void k_bn_apply(float* __restrict__ Z, const float* __restrict__ bnsum,
                                                  const float* __restrict__ bnsq, const float* __restrict__ g,
                                                  const float* __restrict__ bt) {
  __shared__ float s_scale[256], s_shift[256];
  const int t = threadIdx.x;
  {
    float mu = bnsum[t] * (1.f / NN);
    float var = bnsq[t] * (1.f / NN) - mu * mu;
    var = var > 0.f ? var : 0.f;
    float rs = rsqrtf(var + 1e-5f);
    float sc = g[t] * rs;
    s_scale[t] = sc;
    s_shift[t] = bt[t] - mu * sc;
  }
  __syncthreads();
  const int total4 = NN * 64;  // float4 count
  for (int idx = blockIdx.x * 256 + t; idx < total4; idx += gridDim.x * 256) {
    float4 z = reinterpret_cast<float4*>(Z)[idx];
    int col4 = (idx & 63) * 4;
    float4 h;
    h.x = fmaxf(z.x * s_scale[col4 + 0] + s_shift[col4 + 0], 0.f);
    h.y = fmaxf(z.y * s_scale[col4 + 1] + s_shift[col4 + 1], 0.f);
    h.z = fmaxf(z.z * s_scale[col4 + 2] + s_shift[col4 + 2], 0.f);
    h.w = fmaxf(z.w * s_scale[col4 + 3] + s_shift[col4 + 3], 0.f);
    reinterpret_cast<float4*>(Z)[idx] = h;
  }
}

// ---------------- launch ----------------

extern "C" void kernel_launch(void* const* d_in, const int* in_sizes, int n_in,
                              void* d_out, int out_size, void* d_ws, size_t ws_size,
                              hipStream_t stream) {
  const float* x    = (const float*)d_in[0];
  const int*   ei   = (const int*)d_in[1];
  const float* ew   = (const float*)d_in[2];
  const float* W1_0 = (const float*)d_in[3];
  const float* b1_0 = (const float*)d_in[4];
  const float* W2_0 = (const float*)d_in[5];
  const float* b2_0 = (const float*)d_in[6];
  const float* g0   = (const float*)d_in[7];
  const float* bt0  = (const float*)d_in[8];
  const float* W1_1 = (const float*)d_in[9];
  const float* b1_1 = (const float*)d_in[10];
  const float* W2_1 = (const float*)d_in[11];
  const float* b2_1 = (const float*)d_in[12];
  const float* g1   = (const float*)d_in[13];
  const float* bt1  = (const float*)d_in[14];
  const float* encW = (const float*)d_in[15];
  const float* encb = (const float*)d_in[16];

  const int* srcA = ei;
  const int* dstA = ei + NE;

  float* out_enc = (float*)d_out;
  float* out1 = out_enc + (size_t)NN * FDIM;
  float* out2 = out1 + (size_t)NN * FDIM;
  float* Pbuf = out_enc;  // enc region doubles as P scratch; enc is computed last

  char* wp = (char*)d_ws;
  auto carve = [&](size_t bytes) {
    char* r = wp;
    wp += (bytes + 255) & ~(size_t)255;
    return r;
  };
  int*   deg    = (int*)carve((size_t)NN * 4);
  int*   offs   = (int*)carve((size_t)(NN + 1) * 4);
  int*   fillp  = (int*)carve((size_t)NN * 4);
  int2*  pairs  = (int2*)carve((size_t)NE * 8);
  float* bnsum0 = (float*)carve(256 * 4);
  float* bnsq0  = (float*)carve(256 * 4);
  float* bnsum1 = (float*)carve(256 * 4);
  float* bnsq1  = (float*)carve(256 * 4);

  hipMemsetAsync(deg, 0, (size_t)NN * 4, stream);
  hipMemsetAsync(bnsum0, 0, 4 * 256 * 4, stream);  // bnsum0,bnsq0,bnsum1,bnsq1 are contiguous

  k_hist<<<(NE + 255) / 256, 256, 0, stream>>>(dstA, deg);
  k_scan<<<1, 1024, 0, stream>>>(deg, offs, fillp);
  k_fill<<<(NE + 255) / 256, 256, 0, stream>>>(srcA, dstA, fillp, pairs);

  // layer 1
  k_proj1<<<NN / 8, 256, 0, stream>>>(x, W1_0, Pbuf);
  k_agg_mlp<<<(NN + NPB - 1) / NPB, 256, 0, stream>>>(Pbuf, offs, pairs, ew, b1_0, W2_0, b2_0,
                                                      out1, bnsum0, bnsq0);
  k_bn_apply<<<2048, 256, 0, stream>>>(out1, bnsum0, bnsq0, g0, bt0);

  // layer 2
  k_proj_bd<<<NN / 16, 256, 0, stream>>>(out1, W1_1, Pbuf);
  k_agg_mlp<<<(NN + NPB - 1) / NPB, 256, 0, stream>>>(Pbuf, offs, pairs, ew, b1_1, W2_1, b2_1,
                                                      out2, bnsum1, bnsq1);
  k_bn_apply<<<2048, 256, 0, stream>>>(out2, bnsum1, bnsq1, g1, bt1);

  // encoder last (overwrites Pbuf region with final enc output)
  k_enc<<<NN / 8, 256, 0, stream>>>(x, encW, encb, out_enc);
}